// Round 1
// baseline (1847.344 us; speedup 1.0000x reference)
//
#include <hip/hip_runtime.h>
#include <hip/hip_bf16.h>

// ---------------------------------------------------------------------------
// lora_cross_attention: q/k/v proj (split-bf16 MFMA GEMM) -> fused attention
// (bf16 MFMA, online full-row softmax, Sk=77) -> out proj (split-bf16 GEMM).
// Shapes: B=32, Sq=1024, Sk=77, H=8, hd=192, D=1536.
// ---------------------------------------------------------------------------

typedef __attribute__((ext_vector_type(8))) short bf16x8;
typedef __attribute__((ext_vector_type(4))) float f32x4;
typedef __attribute__((ext_vector_type(4))) short s16x4;

#define MFMA16(a, b, c) __builtin_amdgcn_mfma_f32_16x16x32_bf16(a, b, c, 0, 0, 0)

__device__ __forceinline__ unsigned short f2bf(float x) {
    unsigned int u = __float_as_uint(x);
    u += 0x7FFFu + ((u >> 16) & 1u);   // RNE (inputs finite)
    return (unsigned short)(u >> 16);
}
__device__ __forceinline__ float bf2f(unsigned short b) {
    return __uint_as_float(((unsigned int)b) << 16);
}

// ---------------------------------------------------------------------------
// C[M,N] = A[M,K] * B[N,K]^T + bias[N], fp32 in/out, split-bf16 internally.
// 128x128 block tile, 4 waves in 2x2 (64x64 each), BK=32.
// LDS rows padded to 40 bf16 (80 B: 16B-aligned, 2-way bank access = free).
// ---------------------------------------------------------------------------
#define BM 128
#define BN 128
#define LDP 40

__global__ void gemm_nt_split(const float* __restrict__ A,
                              const float* __restrict__ B,
                              const float* __restrict__ bias,
                              float* __restrict__ C,
                              int M, int N, int K) {
    __shared__ unsigned short Ahi[BM * LDP];
    __shared__ unsigned short Alo[BM * LDP];
    __shared__ unsigned short Bhi[BN * LDP];
    __shared__ unsigned short Blo[BN * LDP];

    const int t = threadIdx.x;
    const int lane = t & 63;
    const int wave = t >> 6;
    const int wm = wave >> 1, wn = wave & 1;
    const int row0 = blockIdx.x * BM, col0 = blockIdx.y * BN;

    // staging: thread t handles 16 A floats + 16 B floats per K-step
    const int srow = t >> 1;
    const int scol = (t & 1) << 4;
    const bool aval = (row0 + srow) < M;        // N always divides 128
    const float* Ap = A + (size_t)(row0 + srow) * K + scol;
    const float* Bp = B + (size_t)(col0 + srow) * K + scol;

    const int l15 = lane & 15;
    const int koff = (lane >> 4) << 3;

    f32x4 acc[4][4] = {};

    for (int kt = 0; kt < K; kt += 32) {
        float av[16], bv[16];
#pragma unroll
        for (int i = 0; i < 4; ++i) {
            f32x4 a4 = aval ? *(const f32x4*)(Ap + kt + i * 4)
                            : (f32x4){0.f, 0.f, 0.f, 0.f};
            f32x4 b4 = *(const f32x4*)(Bp + kt + i * 4);
#pragma unroll
            for (int j = 0; j < 4; ++j) { av[i * 4 + j] = a4[j]; bv[i * 4 + j] = b4[j]; }
        }
        unsigned short ah[16], al[16], bh[16], bl[16];
#pragma unroll
        for (int i = 0; i < 16; ++i) {
            unsigned short h = f2bf(av[i]);
            ah[i] = h; al[i] = f2bf(av[i] - bf2f(h));
            unsigned short g = f2bf(bv[i]);
            bh[i] = g; bl[i] = f2bf(bv[i] - bf2f(g));
        }
        __syncthreads();   // previous iteration's LDS reads complete
        const int so = srow * LDP + scol;
        *(bf16x8*)&Ahi[so]     = *(bf16x8*)&ah[0];
        *(bf16x8*)&Ahi[so + 8] = *(bf16x8*)&ah[8];
        *(bf16x8*)&Alo[so]     = *(bf16x8*)&al[0];
        *(bf16x8*)&Alo[so + 8] = *(bf16x8*)&al[8];
        *(bf16x8*)&Bhi[so]     = *(bf16x8*)&bh[0];
        *(bf16x8*)&Bhi[so + 8] = *(bf16x8*)&bh[8];
        *(bf16x8*)&Blo[so]     = *(bf16x8*)&bl[0];
        *(bf16x8*)&Blo[so + 8] = *(bf16x8*)&bl[8];
        __syncthreads();

        bf16x8 afh[4], afl[4], bfh[4], bfl[4];
#pragma unroll
        for (int f = 0; f < 4; ++f) {
            const int ao = (wm * 64 + f * 16 + l15) * LDP + koff;
            const int bo = (wn * 64 + f * 16 + l15) * LDP + koff;
            afh[f] = *(const bf16x8*)&Ahi[ao];
            afl[f] = *(const bf16x8*)&Alo[ao];
            bfh[f] = *(const bf16x8*)&Bhi[bo];
            bfl[f] = *(const bf16x8*)&Blo[bo];
        }
#pragma unroll
        for (int mf = 0; mf < 4; ++mf)
#pragma unroll
            for (int nf = 0; nf < 4; ++nf) {
                f32x4 c = acc[mf][nf];
                c = MFMA16(afh[mf], bfh[nf], c);
                c = MFMA16(afh[mf], bfl[nf], c);
                c = MFMA16(afl[mf], bfh[nf], c);
                acc[mf][nf] = c;
            }
    }

    // epilogue: C = acc + bias
#pragma unroll
    for (int mf = 0; mf < 4; ++mf) {
        const int row = row0 + wm * 64 + mf * 16 + ((lane >> 4) << 2);
#pragma unroll
        for (int nf = 0; nf < 4; ++nf) {
            const int col = col0 + wn * 64 + nf * 16 + l15;
            const float bs = bias[col];
#pragma unroll
            for (int r = 0; r < 4; ++r) {
                if (row + r < M)
                    C[(size_t)(row + r) * N + col] = acc[mf][nf][r] + bs;
            }
        }
    }
}

// ---------------------------------------------------------------------------
// Fused attention: one block per (qtile=64 rows, head, batch). 4 waves, each
// owns 16 q-rows. Sk=77 processed in one shot (padded to 80/96).
// K: LDS row-major [80][200]. V: transposed LDS [96 d][104 s], two d-halves.
// P (unnormalized softmax probs): LDS [64][104]; division folded into O write.
// O written IN-PLACE over qbuf (each wave reads exactly what it overwrites,
// Q is register-resident before any store).
// ---------------------------------------------------------------------------
#define ALDK 200
#define ALDP 104

__global__ void attn_fused(const float* __restrict__ qbuf,
                           const float* __restrict__ kbuf,
                           const float* __restrict__ vbuf,
                           float* __restrict__ obuf) {
    __shared__ unsigned short Ks[80 * ALDK];   // 32000 B
    __shared__ unsigned short Pls[64 * ALDP];  // 13312 B
    __shared__ unsigned short Vt[96 * ALDP];   // 19968 B  (total 65280 <= 64KB)

    const int t = threadIdx.x, lane = t & 63, w = t >> 6;
    const int qt = blockIdx.x, h = blockIdx.y, b = blockIdx.z;
    const int l15 = lane & 15, lhi = lane >> 4;

    // ---- Q fragments: global fp32 -> bf16 registers (A-frag layout) ----
    bf16x8 qf[6];
    {
        const size_t qrow = (size_t)(b * 1024 + qt * 64 + w * 16 + l15);
        const float* qp = qbuf + qrow * 1536 + h * 192 + (lhi << 3);
#pragma unroll
        for (int kt = 0; kt < 6; ++kt) {
            f32x4 x0 = *(const f32x4*)(qp + kt * 32);
            f32x4 x1 = *(const f32x4*)(qp + kt * 32 + 4);
            unsigned short tmp[8];
#pragma unroll
            for (int j = 0; j < 4; ++j) { tmp[j] = f2bf(x0[j]); tmp[4 + j] = f2bf(x1[j]); }
            qf[kt] = *(bf16x8*)tmp;
        }
    }

    // ---- stage K [80][192] (rows >=77 zero) ----
    for (int idx = t; idx < 80 * 192; idx += 256) {
        const int s = idx / 192, d = idx - s * 192;
        const float val = (s < 77) ? kbuf[(size_t)(b * 77 + s) * 1536 + h * 192 + d] : 0.f;
        Ks[s * ALDK + d] = f2bf(val);
    }
    // ---- stage V^T half 0: d in [0,96) ----
    for (int idx = t; idx < 96 * 96; idx += 256) {
        const int s = idx / 96, dd = idx - s * 96;
        const float val = (s < 77) ? vbuf[(size_t)(b * 77 + s) * 1536 + h * 192 + dd] : 0.f;
        Vt[dd * ALDP + s] = f2bf(val);
    }
    // ---- zero P pad cols 80..95 (own rows) ----
    {
        const int row = w * 16 + l15;
        s16x4 z = {0, 0, 0, 0};
        *(s16x4*)&Pls[row * ALDP + 80 + (lhi << 2)] = z;
    }
    __syncthreads();

    // ---- scores: S[16 rows][80 cols] per wave ----
    f32x4 sacc[5] = {};
#pragma unroll
    for (int kt = 0; kt < 6; ++kt) {
#pragma unroll
        for (int nf = 0; nf < 5; ++nf) {
            bf16x8 kf = *(const bf16x8*)&Ks[(nf * 16 + l15) * ALDK + kt * 32 + (lhi << 3)];
            sacc[nf] = MFMA16(qf[kt], kf, sacc[nf]);
        }
    }

    // ---- softmax (row = 16-lane group x reg). p left unnormalized. ----
    float psum[4];
    const float scale = 0.07216878364870323f;  // 192^-0.5
#pragma unroll
    for (int r = 0; r < 4; ++r) {
        float m = -1e30f;
#pragma unroll
        for (int nf = 0; nf < 5; ++nf) {
            const int c = nf * 16 + l15;
            const float sv = sacc[nf][r] * scale;
            if (c < 77) m = fmaxf(m, sv);
        }
#pragma unroll
        for (int off = 1; off < 16; off <<= 1) m = fmaxf(m, __shfl_xor(m, off));
        float sum = 0.f;
#pragma unroll
        for (int nf = 0; nf < 5; ++nf) {
            const int c = nf * 16 + l15;
            const float p = (c < 77) ? __expf(sacc[nf][r] * scale - m) : 0.f;
            sacc[nf][r] = p;
            sum += p;
        }
#pragma unroll
        for (int off = 1; off < 16; off <<= 1) sum += __shfl_xor(sum, off);
        psum[r] = sum;
    }

    // ---- write P (own 16 rows) ----
#pragma unroll
    for (int r = 0; r < 4; ++r)
#pragma unroll
        for (int nf = 0; nf < 5; ++nf)
            Pls[(w * 16 + (lhi << 2) + r) * ALDP + nf * 16 + l15] = f2bf(sacc[nf][r]);
    __syncthreads();

    // ---- P A-fragments (own rows, k = s) ----
    bf16x8 pa[3];
#pragma unroll
    for (int kt = 0; kt < 3; ++kt)
        pa[kt] = *(const bf16x8*)&Pls[(w * 16 + l15) * ALDP + kt * 32 + (lhi << 3)];

    const size_t orow = (size_t)(b * 1024 + qt * 64 + w * 16 + (lhi << 2));

    // ---- PV half 0 ----
    {
        f32x4 oacc[6] = {};
#pragma unroll
        for (int kt = 0; kt < 3; ++kt)
#pragma unroll
            for (int nf = 0; nf < 6; ++nf) {
                bf16x8 vf = *(const bf16x8*)&Vt[(nf * 16 + l15) * ALDP + kt * 32 + (lhi << 3)];
                oacc[nf] = MFMA16(pa[kt], vf, oacc[nf]);
            }
#pragma unroll
        for (int nf = 0; nf < 6; ++nf) {
            const int col = h * 192 + nf * 16 + l15;
#pragma unroll
            for (int r = 0; r < 4; ++r)
                obuf[(orow + r) * 1536 + col] = oacc[nf][r] / psum[r];
        }
    }
    __syncthreads();
    // ---- stage V^T half 1: d in [96,192) ----
    for (int idx = t; idx < 96 * 96; idx += 256) {
        const int s = idx / 96, dd = idx - s * 96;
        const float val = (s < 77) ? vbuf[(size_t)(b * 77 + s) * 1536 + h * 192 + 96 + dd] : 0.f;
        Vt[dd * ALDP + s] = f2bf(val);
    }
    __syncthreads();
    // ---- PV half 1 ----
    {
        f32x4 oacc[6] = {};
#pragma unroll
        for (int kt = 0; kt < 3; ++kt)
#pragma unroll
            for (int nf = 0; nf < 6; ++nf) {
                bf16x8 vf = *(const bf16x8*)&Vt[(nf * 16 + l15) * ALDP + kt * 32 + (lhi << 3)];
                oacc[nf] = MFMA16(pa[kt], vf, oacc[nf]);
            }
#pragma unroll
        for (int nf = 0; nf < 6; ++nf) {
            const int col = h * 192 + 96 + nf * 16 + l15;
#pragma unroll
            for (int r = 0; r < 4; ++r)
                obuf[(orow + r) * 1536 + col] = oacc[nf][r] / psum[r];
        }
    }
}

// ---------------------------------------------------------------------------
extern "C" void kernel_launch(void* const* d_in, const int* in_sizes, int n_in,
                              void* d_out, int out_size, void* d_ws, size_t ws_size,
                              hipStream_t stream) {
    const float* img  = (const float*)d_in[0];
    const float* text = (const float*)d_in[1];
    const float* Wq   = (const float*)d_in[2];
    const float* bq   = (const float*)d_in[3];
    const float* Wk   = (const float*)d_in[4];
    const float* bk   = (const float*)d_in[5];
    const float* Wv   = (const float*)d_in[6];
    const float* bv   = (const float*)d_in[7];
    const float* Wo   = (const float*)d_in[8];
    const float* bo   = (const float*)d_in[9];

    // workspace: q [32768,1536] f32 | k [2464,1536] | v [2464,1536]  (~221 MB)
    float* q = (float*)d_ws;
    float* k = q + (size_t)32768 * 1536;
    float* v = k + (size_t)2464 * 1536;
    float* out = (float*)d_out;

    dim3 blk(256);
    hipLaunchKernelGGL(gemm_nt_split, dim3(256, 12), blk, 0, stream,
                       img, Wq, bq, q, 32768, 1536, 1536);
    hipLaunchKernelGGL(gemm_nt_split, dim3(20, 12), blk, 0, stream,
                       text, Wk, bk, k, 2464, 1536, 1536);
    hipLaunchKernelGGL(gemm_nt_split, dim3(20, 12), blk, 0, stream,
                       text, Wv, bv, v, 2464, 1536, 1536);
    // attention writes O in-place over q (per-wave read-then-write, disjoint)
    hipLaunchKernelGGL(attn_fused, dim3(16, 8, 32), blk, 0, stream,
                       q, k, v, q);
    hipLaunchKernelGGL(gemm_nt_split, dim3(256, 12), blk, 0, stream,
                       q, Wo, bo, out, 32768, 1536, 1536);
}

// Round 2
// 1156.653 us; speedup vs baseline: 1.5971x; 1.5971x over previous
//
#include <hip/hip_runtime.h>
#include <hip/hip_bf16.h>

// ---------------------------------------------------------------------------
// lora_cross_attention, round 2.
// Dataflow: split(img->hi; text,W*->hi+lo)  ->  q = imgHi x Wq (2-combo bf16
// MFMA, bf16 out) -> k,v (3-combo, bf16 out, fused launch) -> fused attention
// (bf16 in, O emitted as hi/lo bf16 split) -> out = O x Wo (3-combo, f32 out).
// GEMMs: 128x128 tile, BK=32, global_load_lds(16B) staging, XOR-swizzled LDS,
// XCD-bijective block swizzle.  ws use ~270 MB.
// ---------------------------------------------------------------------------

typedef unsigned short u16;
typedef __attribute__((ext_vector_type(8))) short bf16x8;
typedef __attribute__((ext_vector_type(4))) float f32x4;
typedef __attribute__((ext_vector_type(4))) short s16x4;

#define MFMA16(a, b, c) __builtin_amdgcn_mfma_f32_16x16x32_bf16(a, b, c, 0, 0, 0)

__device__ __forceinline__ u16 f2bf(float x) {
    unsigned int u = __float_as_uint(x);
    u += 0x7FFFu + ((u >> 16) & 1u);   // RNE (finite inputs)
    return (u16)(u >> 16);
}
__device__ __forceinline__ float bf2f(u16 b) {
    return __uint_as_float(((unsigned int)b) << 16);
}

__device__ __forceinline__ void gload16(const u16* g, const u16* l) {
    __builtin_amdgcn_global_load_lds(
        (const __attribute__((address_space(1))) unsigned int*)g,
        (__attribute__((address_space(3))) unsigned int*)l, 16, 0, 0);
}

// chunk swizzle: spreads stride-64B rows across bank quads (involution)
__device__ __forceinline__ int swz(int r) { return (r & 3) ^ ((r >> 2) & 3); }

// ---------------------------------------------------------------------------
// split kernels: fp32 -> bf16 hi (+ lo residual)
// ---------------------------------------------------------------------------
__global__ void split_hi_only(const float* __restrict__ x, u16* __restrict__ hi, int n8) {
    const int i = blockIdx.x * 256 + threadIdx.x;
    if (i >= n8) return;
    const f32x4 a = ((const f32x4*)x)[2 * i];
    const f32x4 b = ((const f32x4*)x)[2 * i + 1];
    u16 h[8];
#pragma unroll
    for (int j = 0; j < 4; ++j) { h[j] = f2bf(a[j]); h[4 + j] = f2bf(b[j]); }
    *(bf16x8*)&hi[(size_t)i << 3] = *(bf16x8*)h;
}

struct Split5Args {
    const float* x[5];
    u16* h[5];
    u16* l[5];
    int n8[5];
};

__global__ void split_hilo5(Split5Args A) {
    const int z = blockIdx.y;
    const int i = blockIdx.x * 256 + threadIdx.x;
    if (i >= A.n8[z]) return;
    const float* x = A.x[z];
    const f32x4 a = ((const f32x4*)x)[2 * i];
    const f32x4 b = ((const f32x4*)x)[2 * i + 1];
    u16 h[8], l[8];
#pragma unroll
    for (int j = 0; j < 4; ++j) {
        h[j] = f2bf(a[j]);       l[j] = f2bf(a[j] - bf2f(h[j]));
        h[4 + j] = f2bf(b[j]);   l[4 + j] = f2bf(b[j] - bf2f(h[4 + j]));
    }
    *(bf16x8*)&A.h[z][(size_t)i << 3] = *(bf16x8*)h;
    *(bf16x8*)&A.l[z][(size_t)i << 3] = *(bf16x8*)l;
}

// ---------------------------------------------------------------------------
// C[M,N] = (Ahi[+Alo]) x (Bhi+Blo)^T + bias   (split-bf16, NT layout)
// COMBOS=2: Ahi*Bhi + Ahi*Blo (A pre-rounded to bf16 is good enough)
// COMBOS=3: + Alo*Bhi.  OUTF32: fp32 C, else bf16 C.
// grid.z selects (B,bias,C) set 0/1 (used to fuse the k and v projections).
// ---------------------------------------------------------------------------
template <int COMBOS, int OUTF32>
__global__ __launch_bounds__(256, 2) void gemm_split_nt(
    const u16* __restrict__ Ahi, const u16* __restrict__ Alo,
    const u16* __restrict__ Bhi0, const u16* __restrict__ Blo0,
    const float* __restrict__ bias0, void* __restrict__ C0,
    const u16* __restrict__ Bhi1, const u16* __restrict__ Blo1,
    const float* __restrict__ bias1, void* __restrict__ C1,
    int M, int N, int K, int nby) {
    constexpr int NT = (COMBOS == 3) ? 4 : 3;
    __shared__ u16 lds[NT * 4096];   // tiles: 0=Ahi 1=Bhi 2=Blo [3=Alo]

    const u16* Bhi = Bhi0; const u16* Blo = Blo0;
    const float* bias = bias0; void* Cout = C0;
    if (blockIdx.z) { Bhi = Bhi1; Blo = Blo1; bias = bias1; Cout = C1; }

    // XCD-bijective block swizzle (m204)
    const int nwg = gridDim.x;
    const int q8 = nwg >> 3, r8 = nwg & 7;
    const int xcd = blockIdx.x & 7, loc = blockIdx.x >> 3;
    const int wgid = (xcd < r8 ? xcd * (q8 + 1) : r8 * (q8 + 1) + (xcd - r8) * q8) + loc;
    const int bx = wgid / nby, by = wgid - bx * nby;
    const int row0 = bx * 128, col0 = by * 128;

    const int t = threadIdx.x, lane = t & 63, w = t >> 6;
    const int wm = w >> 1, wn = w & 1;
    const int l15 = lane & 15, lhi = lane >> 4;

    // staging geometry: per wave, 2 chunks (1024B) per tile; lane l fills
    // LDS slot (row = ch*16 + l/4, 16B-chunk = l%4); global source chunk is
    // pre-swizzled so swizzled ds_reads see linear data (rule 21).
    const int l2 = lane >> 2, c4 = lane & 3;
    const u16* gA[2]; const u16* gAl[2]; const u16* gBh[2]; const u16* gBl[2];
    const u16 *lA[2], *lAl[2], *lBh[2], *lBl[2];
#pragma unroll
    for (int j = 0; j < 2; ++j) {
        const int ch = 2 * w + j;
        const int rr = ch * 16 + l2;
        const int gc = (c4 ^ swz(rr)) << 3;
        int ar = row0 + rr; if (ar > M - 1) ar = M - 1;   // tail clamp (stores guarded)
        gA[j]  = Ahi + (size_t)ar * K + gc;
        gBh[j] = Bhi + (size_t)(col0 + rr) * K + gc;
        gBl[j] = Blo + (size_t)(col0 + rr) * K + gc;
        lA[j]  = lds + ch * 512;
        lBh[j] = lds + 4096 + ch * 512;
        lBl[j] = lds + 2 * 4096 + ch * 512;
        if (COMBOS == 3) {
            gAl[j] = Alo + (size_t)ar * K + gc;
            lAl[j] = lds + 3 * 4096 + ch * 512;
        }
    }

    // fragment read offsets (swizzled)
    int aoff[4], boff[4];
#pragma unroll
    for (int f = 0; f < 4; ++f) {
        const int ar = wm * 64 + f * 16 + l15;
        aoff[f] = ar * 32 + ((lhi ^ swz(ar)) << 3);
        const int br = wn * 64 + f * 16 + l15;
        boff[f] = br * 32 + ((lhi ^ swz(br)) << 3);
    }

    f32x4 acc[4][4] = {};

    for (int kt = 0; kt < K; kt += 32) {
        if (kt) __syncthreads();   // prior reads done before overwrite
#pragma unroll
        for (int j = 0; j < 2; ++j) {
            gload16(gA[j] + kt, lA[j]);
            gload16(gBh[j] + kt, lBh[j]);
            gload16(gBl[j] + kt, lBl[j]);
            if (COMBOS == 3) gload16(gAl[j] + kt, lAl[j]);
        }
        __syncthreads();           // compiler drains vmcnt before barrier

        bf16x8 ah[4], al[4];
#pragma unroll
        for (int f = 0; f < 4; ++f) {
            ah[f] = *(const bf16x8*)&lds[aoff[f]];
            if (COMBOS == 3) al[f] = *(const bf16x8*)&lds[3 * 4096 + aoff[f]];
        }
#pragma unroll
        for (int nf = 0; nf < 4; ++nf) {
            const bf16x8 bh = *(const bf16x8*)&lds[4096 + boff[nf]];
            const bf16x8 bl = *(const bf16x8*)&lds[2 * 4096 + boff[nf]];
#pragma unroll
            for (int mf = 0; mf < 4; ++mf) {
                f32x4 c = acc[mf][nf];
                c = MFMA16(ah[mf], bh, c);
                c = MFMA16(ah[mf], bl, c);
                if (COMBOS == 3) c = MFMA16(al[mf], bh, c);
                acc[mf][nf] = c;
            }
        }
    }

    // epilogue: +bias, store (C/D layout: col=lane&15, row=lhi*4+reg)
#pragma unroll
    for (int nf = 0; nf < 4; ++nf) {
        const int col = col0 + wn * 64 + nf * 16 + l15;
        const float bs = bias[col];
#pragma unroll
        for (int mf = 0; mf < 4; ++mf) {
            const int row = row0 + wm * 64 + mf * 16 + (lhi << 2);
#pragma unroll
            for (int r = 0; r < 4; ++r) {
                if (row + r < M) {
                    const float v = acc[mf][nf][r] + bs;
                    if (OUTF32) ((float*)Cout)[(size_t)(row + r) * N + col] = v;
                    else        ((u16*)Cout)[(size_t)(row + r) * N + col] = f2bf(v);
                }
            }
        }
    }
}

// ---------------------------------------------------------------------------
// Fused attention, bf16 in / split-bf16 out. One block per (qtile=64,h,b),
// 4 waves x 16 q-rows. Sk=77 one-shot. O_lo written IN-PLACE over q (each
// wave reads exactly the rows+head-slice it later writes).
// ---------------------------------------------------------------------------
#define ALDK 200
#define ALDP 104

__global__ void attn_fused(const u16* __restrict__ qbuf, const u16* __restrict__ kbuf,
                           const u16* __restrict__ vbuf, u16* __restrict__ ohi,
                           u16* __restrict__ olo) {
    __shared__ u16 Ks[80 * ALDK];   // 32000 B
    __shared__ u16 Pls[64 * ALDP];  // 13312 B
    __shared__ u16 Vt[96 * ALDP];   // 19968 B (65280 total)

    const int t = threadIdx.x, lane = t & 63, w = t >> 6;
    const int qt = blockIdx.x, h = blockIdx.y, b = blockIdx.z;
    const int l15 = lane & 15, lhi = lane >> 4;

    // Q fragments straight from global bf16
    bf16x8 qf[6];
    {
        const size_t qrow = (size_t)(b * 1024 + qt * 64 + w * 16 + l15);
        const u16* qp = qbuf + qrow * 1536 + h * 192 + (lhi << 3);
#pragma unroll
        for (int kt = 0; kt < 6; ++kt) qf[kt] = *(const bf16x8*)(qp + kt * 32);
    }

    // stage K [80][192], rows >=77 zero
    for (int c = t; c < 80 * 24; c += 256) {
        const int s = c / 24, d8 = (c - s * 24) << 3;
        bf16x8 val = {};
        if (s < 77) val = *(const bf16x8*)&kbuf[(size_t)(b * 77 + s) * 1536 + h * 192 + d8];
        *(bf16x8*)&Ks[s * ALDK + d8] = val;
    }
    // stage V^T half 0: d in [0,96)
    for (int c = t; c < 96 * 12; c += 256) {
        const int s = c / 12, d8 = (c - s * 12) << 3;
        bf16x8 val = {};
        if (s < 77) val = *(const bf16x8*)&vbuf[(size_t)(b * 77 + s) * 1536 + h * 192 + d8];
#pragma unroll
        for (int j = 0; j < 8; ++j) Vt[(d8 + j) * ALDP + s] = (u16)val[j];
    }
    // zero P pad cols 80..95 (own rows)
    {
        const int row = w * 16 + l15;
        s16x4 z = {0, 0, 0, 0};
        *(s16x4*)&Pls[row * ALDP + 80 + (lhi << 2)] = z;
    }
    __syncthreads();

    // scores S[16 q-rows][80 k-cols] per wave
    f32x4 sacc[5] = {};
#pragma unroll
    for (int kt = 0; kt < 6; ++kt) {
#pragma unroll
        for (int nf = 0; nf < 5; ++nf) {
            bf16x8 kf = *(const bf16x8*)&Ks[(nf * 16 + l15) * ALDK + kt * 32 + (lhi << 3)];
            sacc[nf] = MFMA16(qf[kt], kf, sacc[nf]);
        }
    }

    // softmax per q-row (row = lhi*4 + r); P kept unnormalized
    float rps[4];
    const float scale = 0.07216878364870323f;   // 192^-0.5
#pragma unroll
    for (int r = 0; r < 4; ++r) {
        float m = -1e30f;
#pragma unroll
        for (int nf = 0; nf < 5; ++nf) {
            const int c = nf * 16 + l15;
            const float sv = sacc[nf][r] * scale;
            if (c < 77) m = fmaxf(m, sv);
        }
#pragma unroll
        for (int off = 1; off < 16; off <<= 1) m = fmaxf(m, __shfl_xor(m, off));
        float sum = 0.f;
#pragma unroll
        for (int nf = 0; nf < 5; ++nf) {
            const int c = nf * 16 + l15;
            const float p = (c < 77) ? __expf(sacc[nf][r] * scale - m) : 0.f;
            sacc[nf][r] = p;
            sum += p;
        }
#pragma unroll
        for (int off = 1; off < 16; off <<= 1) sum += __shfl_xor(sum, off);
        rps[r] = 1.0f / sum;   // sum >= 1
    }

    // write P (own 16 rows)
#pragma unroll
    for (int r = 0; r < 4; ++r)
#pragma unroll
        for (int nf = 0; nf < 5; ++nf)
            Pls[(w * 16 + (lhi << 2) + r) * ALDP + nf * 16 + l15] = f2bf(sacc[nf][r]);
    __syncthreads();

    // P A-fragments
    bf16x8 pa[3];
#pragma unroll
    for (int kt = 0; kt < 3; ++kt)
        pa[kt] = *(const bf16x8*)&Pls[(w * 16 + l15) * ALDP + kt * 32 + (lhi << 3)];

    const size_t orow = (size_t)(b * 1024 + qt * 64 + w * 16 + (lhi << 2));

    // PV half 0 -> O[:, 0:96)
    {
        f32x4 oacc[6] = {};
#pragma unroll
        for (int kt = 0; kt < 3; ++kt)
#pragma unroll
            for (int nf = 0; nf < 6; ++nf) {
                bf16x8 vf = *(const bf16x8*)&Vt[(nf * 16 + l15) * ALDP + kt * 32 + (lhi << 3)];
                oacc[nf] = MFMA16(pa[kt], vf, oacc[nf]);
            }
#pragma unroll
        for (int nf = 0; nf < 6; ++nf) {
            const int col = h * 192 + nf * 16 + l15;
#pragma unroll
            for (int r = 0; r < 4; ++r) {
                const float o = oacc[nf][r] * rps[r];
                const u16 hv = f2bf(o);
                ohi[(orow + r) * 1536 + col] = hv;
                olo[(orow + r) * 1536 + col] = f2bf(o - bf2f(hv));
            }
        }
    }
    __syncthreads();
    // stage V^T half 1: d in [96,192)
    for (int c = t; c < 96 * 12; c += 256) {
        const int s = c / 12, d8 = (c - s * 12) << 3;
        bf16x8 val = {};
        if (s < 77) val = *(const bf16x8*)&vbuf[(size_t)(b * 77 + s) * 1536 + h * 192 + 96 + d8];
#pragma unroll
        for (int j = 0; j < 8; ++j) Vt[(d8 + j) * ALDP + s] = (u16)val[j];
    }
    __syncthreads();
    // PV half 1 -> O[:, 96:192)
    {
        f32x4 oacc[6] = {};
#pragma unroll
        for (int kt = 0; kt < 3; ++kt)
#pragma unroll
            for (int nf = 0; nf < 6; ++nf) {
                bf16x8 vf = *(const bf16x8*)&Vt[(nf * 16 + l15) * ALDP + kt * 32 + (lhi << 3)];
                oacc[nf] = MFMA16(pa[kt], vf, oacc[nf]);
            }
#pragma unroll
        for (int nf = 0; nf < 6; ++nf) {
            const int col = h * 192 + 96 + nf * 16 + l15;
#pragma unroll
            for (int r = 0; r < 4; ++r) {
                const float o = oacc[nf][r] * rps[r];
                const u16 hv = f2bf(o);
                ohi[(orow + r) * 1536 + col] = hv;
                olo[(orow + r) * 1536 + col] = f2bf(o - bf2f(hv));
            }
        }
    }
}

// ---------------------------------------------------------------------------
extern "C" void kernel_launch(void* const* d_in, const int* in_sizes, int n_in,
                              void* d_out, int out_size, void* d_ws, size_t ws_size,
                              hipStream_t stream) {
    const float* img  = (const float*)d_in[0];
    const float* text = (const float*)d_in[1];
    const float* Wq   = (const float*)d_in[2];
    const float* bq   = (const float*)d_in[3];
    const float* Wk   = (const float*)d_in[4];
    const float* bk   = (const float*)d_in[5];
    const float* Wv   = (const float*)d_in[6];
    const float* bv   = (const float*)d_in[7];
    const float* Wo   = (const float*)d_in[8];
    const float* bo   = (const float*)d_in[9];

    const size_t imgN = (size_t)32768 * 1536;
    const size_t txtN = (size_t)2464 * 1536;
    const size_t wN   = (size_t)1536 * 1536;

    // ws layout (~270 MB of bf16):
    u16* img_hi = (u16*)d_ws;        // [imgN]  later reused as O_hi
    u16* qb     = img_hi + imgN;     // [imgN]  q bf16, later O_lo (in-place)
    u16* txt_hi = qb + imgN;         // [txtN]
    u16* txt_lo = txt_hi + txtN;     // [txtN]
    u16* Wq_hi  = txt_lo + txtN;  u16* Wq_lo = Wq_hi + wN;
    u16* Wk_hi  = Wq_lo + wN;     u16* Wk_lo = Wk_hi + wN;
    u16* Wv_hi  = Wk_lo + wN;     u16* Wv_lo = Wv_hi + wN;
    u16* Wo_hi  = Wv_lo + wN;     u16* Wo_lo = Wo_hi + wN;
    u16* kb     = Wo_lo + wN;        // [txtN]
    u16* vb     = kb + txtN;         // [txtN]

    // 1) splits
    hipLaunchKernelGGL(split_hi_only, dim3((unsigned)(imgN / 8 / 256)), dim3(256),
                       0, stream, img, img_hi, (int)(imgN / 8));
    Split5Args sa;
    sa.x[0] = text; sa.h[0] = txt_hi; sa.l[0] = txt_lo; sa.n8[0] = (int)(txtN / 8);
    sa.x[1] = Wq;   sa.h[1] = Wq_hi;  sa.l[1] = Wq_lo;  sa.n8[1] = (int)(wN / 8);
    sa.x[2] = Wk;   sa.h[2] = Wk_hi;  sa.l[2] = Wk_lo;  sa.n8[2] = (int)(wN / 8);
    sa.x[3] = Wv;   sa.h[3] = Wv_hi;  sa.l[3] = Wv_lo;  sa.n8[3] = (int)(wN / 8);
    sa.x[4] = Wo;   sa.h[4] = Wo_hi;  sa.l[4] = Wo_lo;  sa.n8[4] = (int)(wN / 8);
    hipLaunchKernelGGL(split_hilo5, dim3((unsigned)((txtN / 8 + 255) / 256), 5),
                       dim3(256), 0, stream, sa);

    // 2) q projection: 2-combo, bf16 out
    hipLaunchKernelGGL((gemm_split_nt<2, 0>), dim3(3072), dim3(256), 0, stream,
                       img_hi, img_hi, Wq_hi, Wq_lo, bq, (void*)qb,
                       Wq_hi, Wq_lo, bq, (void*)qb, 32768, 1536, 1536, 12);
    // 3) k,v projections fused via grid.z: 3-combo, bf16 out
    hipLaunchKernelGGL((gemm_split_nt<3, 0>), dim3(240, 1, 2), dim3(256), 0, stream,
                       txt_hi, txt_lo, Wk_hi, Wk_lo, bk, (void*)kb,
                       Wv_hi, Wv_lo, bv, (void*)vb, 2464, 1536, 1536, 12);
    // 4) attention: O_hi -> img_hi region, O_lo -> qb region (in-place)
    hipLaunchKernelGGL(attn_fused, dim3(16, 8, 32), dim3(256), 0, stream,
                       qb, kb, vb, img_hi, qb);
    // 5) output projection: 3-combo, fp32 out
    hipLaunchKernelGGL((gemm_split_nt<3, 1>), dim3(3072), dim3(256), 0, stream,
                       img_hi, qb, Wo_hi, Wo_lo, bo, d_out,
                       Wo_hi, Wo_lo, bo, d_out, 32768, 1536, 1536, 12);
}

// Round 3
// 674.777 us; speedup vs baseline: 2.7377x; 1.7141x over previous
//
#include <hip/hip_runtime.h>
#include <hip/hip_bf16.h>

// ---------------------------------------------------------------------------
// lora_cross_attention, round 3: all-fp16 single-pass MFMA.
// conv(img,text,W* -> fp16) -> q = img x Wq^T (fp16 MFMA, 128x256 tile)
// -> k,v (fused, grid.z) -> fused attention (fp16, O fp16 in-place over q)
// -> out = O x Wo^T (fp32 out).
// GEMM: 128x256 tile, BK=32, 4 waves (64x128 each), global_load_lds(16B),
// both-sides XOR chunk swizzle, XCD-bijective block swizzle.
// ---------------------------------------------------------------------------

typedef unsigned short u16;
typedef _Float16 f16x8 __attribute__((ext_vector_type(8)));
typedef __attribute__((ext_vector_type(8))) short s16x8;
typedef __attribute__((ext_vector_type(4))) float f32x4;
typedef __attribute__((ext_vector_type(4))) short s16x4;

#define MFMAH(a, b, c) __builtin_amdgcn_mfma_f32_16x16x32_f16(a, b, c, 0, 0, 0)

__device__ __forceinline__ u16 f2h(float x) {
    _Float16 h = (_Float16)x;              // v_cvt_f16_f32, RNE
    return __builtin_bit_cast(u16, h);
}

__device__ __forceinline__ void gload16(const u16* g, const u16* l) {
    __builtin_amdgcn_global_load_lds(
        (const __attribute__((address_space(1))) unsigned int*)g,
        (__attribute__((address_space(3))) unsigned int*)l, 16, 0, 0);
}

// chunk swizzle: spreads stride-64B rows across bank quads (involution)
__device__ __forceinline__ int swz(int r) { return (r & 3) ^ ((r >> 2) & 3); }

// ---------------------------------------------------------------------------
// fp32 -> fp16 conversion
// ---------------------------------------------------------------------------
__global__ void conv_h(const float* __restrict__ x, u16* __restrict__ h, int n8) {
    const int i = blockIdx.x * 256 + threadIdx.x;
    if (i >= n8) return;
    const f32x4 a = ((const f32x4*)x)[2 * i];
    const f32x4 b = ((const f32x4*)x)[2 * i + 1];
    u16 o[8];
#pragma unroll
    for (int j = 0; j < 4; ++j) { o[j] = f2h(a[j]); o[4 + j] = f2h(b[j]); }
    *(s16x8*)&h[(size_t)i << 3] = *(s16x8*)o;
}

struct Conv5Args {
    const float* x[5];
    u16* h[5];
    int n8[5];
};

__global__ void conv_h5(Conv5Args A) {
    const int z = blockIdx.y;
    const int i = blockIdx.x * 256 + threadIdx.x;
    if (i >= A.n8[z]) return;
    const float* x = A.x[z];
    const f32x4 a = ((const f32x4*)x)[2 * i];
    const f32x4 b = ((const f32x4*)x)[2 * i + 1];
    u16 o[8];
#pragma unroll
    for (int j = 0; j < 4; ++j) { o[j] = f2h(a[j]); o[4 + j] = f2h(b[j]); }
    *(s16x8*)&A.h[z][(size_t)i << 3] = *(s16x8*)o;
}

// ---------------------------------------------------------------------------
// C[M,N] = A[M,K] x B[N,K]^T + bias, fp16 in, fp32 or fp16 out.
// 128x256 block tile, BK=32, 4 waves 2x2 (each 64 rows x 128 cols).
// grid.z selects (B,bias,C) set 0/1 (fuses k and v projections).
// ---------------------------------------------------------------------------
template <int OUTF32>
__global__ __launch_bounds__(256, 2) void gemm_h_nt(
    const u16* __restrict__ A,
    const u16* __restrict__ B0, const float* __restrict__ bias0, void* __restrict__ C0,
    const u16* __restrict__ B1, const float* __restrict__ bias1, void* __restrict__ C1,
    int M, int N, int K, int nby) {
    __shared__ u16 lds[12288];   // A tile [128][32] @0, B tile [256][32] @4096

    const u16* B = B0; const float* bias = bias0; void* Cout = C0;
    if (blockIdx.z) { B = B1; bias = bias1; Cout = C1; }

    // XCD-bijective block swizzle (m204)
    const int nwg = gridDim.x;
    const int q8 = nwg >> 3, r8 = nwg & 7;
    const int xcd = blockIdx.x & 7, loc = blockIdx.x >> 3;
    const int wgid = (xcd < r8 ? xcd * (q8 + 1) : r8 * (q8 + 1) + (xcd - r8) * q8) + loc;
    const int bx = wgid / nby, by = wgid - bx * nby;
    const int row0 = bx * 128, col0 = by * 256;

    const int t = threadIdx.x, lane = t & 63, w = t >> 6;
    const int wm = w >> 1, wn = w & 1;
    const int l15 = lane & 15, lhi = lane >> 4;

    // ---- staging geometry: 16B chunks; global source pre-swizzled (rule 21)
    const u16* gA[2]; const u16* gB[4];
    const u16 *lA[2], *lB[4];
#pragma unroll
    for (int j = 0; j < 2; ++j) {
        const int ch = j * 256 + w * 64 + lane;      // 0..511
        const int row = ch >> 2;                     // 0..127
        const int kc = (ch & 3) ^ swz(row);
        int ar = row0 + row; if (ar > M - 1) ar = M - 1;   // tail clamp
        gA[j] = A + (size_t)ar * K + (kc << 3);
        lA[j] = lds + (size_t)(j * 256 + w * 64) * 8;
    }
#pragma unroll
    for (int j = 0; j < 4; ++j) {
        const int ch = j * 256 + w * 64 + lane;      // 0..1023
        const int row = ch >> 2;                     // 0..255
        const int kc = (ch & 3) ^ swz(row);
        gB[j] = B + (size_t)(col0 + row) * K + (kc << 3);
        lB[j] = lds + 4096 + (size_t)(j * 256 + w * 64) * 8;
    }

    // ---- fragment read offsets (swizzled)
    int aoff[4], boff[8];
#pragma unroll
    for (int mf = 0; mf < 4; ++mf) {
        const int ar = wm * 64 + mf * 16 + l15;
        aoff[mf] = ar * 32 + ((lhi ^ swz(ar)) << 3);
    }
#pragma unroll
    for (int nf = 0; nf < 8; ++nf) {
        const int br = wn * 128 + nf * 16 + l15;
        boff[nf] = 4096 + br * 32 + ((lhi ^ swz(br)) << 3);
    }

    f32x4 acc[4][8] = {};

    for (int kt = 0; kt < K; kt += 32) {
        if (kt) __syncthreads();
#pragma unroll
        for (int j = 0; j < 2; ++j) gload16(gA[j] + kt, lA[j]);
#pragma unroll
        for (int j = 0; j < 4; ++j) gload16(gB[j] + kt, lB[j]);
        __syncthreads();           // compiler drains vmcnt before barrier

        f16x8 a[4];
#pragma unroll
        for (int mf = 0; mf < 4; ++mf) a[mf] = *(const f16x8*)&lds[aoff[mf]];
#pragma unroll
        for (int nf = 0; nf < 8; ++nf) {
            const f16x8 b = *(const f16x8*)&lds[boff[nf]];
#pragma unroll
            for (int mf = 0; mf < 4; ++mf)
                acc[mf][nf] = MFMAH(a[mf], b, acc[mf][nf]);
        }
    }

    // ---- epilogue: +bias, store (C/D: col=lane&15, row=lhi*4+reg)
#pragma unroll
    for (int nf = 0; nf < 8; ++nf) {
        const int col = col0 + wn * 128 + nf * 16 + l15;
        const float bs = bias[col];
#pragma unroll
        for (int mf = 0; mf < 4; ++mf) {
            const int row = row0 + wm * 64 + mf * 16 + (lhi << 2);
#pragma unroll
            for (int r = 0; r < 4; ++r) {
                if (row + r < M) {
                    const float v = acc[mf][nf][r] + bs;
                    if (OUTF32) ((float*)Cout)[(size_t)(row + r) * N + col] = v;
                    else        ((u16*)Cout)[(size_t)(row + r) * N + col] = f2h(v);
                }
            }
        }
    }
}

// ---------------------------------------------------------------------------
// Fused attention, fp16 in/out. One block per (qtile=64,h,b), 4 waves x 16
// q-rows. Sk=77 one-shot. O written IN-PLACE over q (each wave reads exactly
// the rows+head-slice it later writes; Q register-resident first).
// ---------------------------------------------------------------------------
#define ALDK 200
#define ALDP 104

__global__ void attn_fused(const u16* __restrict__ qbuf, const u16* __restrict__ kbuf,
                           const u16* __restrict__ vbuf, u16* __restrict__ obuf) {
    __shared__ u16 Ks[80 * ALDK];   // 32000 B
    __shared__ u16 Pls[64 * ALDP];  // 13312 B
    __shared__ u16 Vt[96 * ALDP];   // 19968 B (65280 total)

    const int t = threadIdx.x, lane = t & 63, w = t >> 6;
    const int qt = blockIdx.x, h = blockIdx.y, b = blockIdx.z;
    const int l15 = lane & 15, lhi = lane >> 4;

    // Q fragments straight from global fp16
    f16x8 qf[6];
    {
        const size_t qrow = (size_t)(b * 1024 + qt * 64 + w * 16 + l15);
        const u16* qp = qbuf + qrow * 1536 + h * 192 + (lhi << 3);
#pragma unroll
        for (int kt = 0; kt < 6; ++kt) qf[kt] = *(const f16x8*)(qp + kt * 32);
    }

    // stage K [80][192], rows >=77 zero (raw u16 copy)
    for (int c = t; c < 80 * 24; c += 256) {
        const int s = c / 24, d8 = (c - s * 24) << 3;
        s16x8 val = {};
        if (s < 77) val = *(const s16x8*)&kbuf[(size_t)(b * 77 + s) * 1536 + h * 192 + d8];
        *(s16x8*)&Ks[s * ALDK + d8] = val;
    }
    // stage V^T half 0: d in [0,96)
    for (int c = t; c < 96 * 12; c += 256) {
        const int s = c / 12, d8 = (c - s * 12) << 3;
        s16x8 val = {};
        if (s < 77) val = *(const s16x8*)&vbuf[(size_t)(b * 77 + s) * 1536 + h * 192 + d8];
#pragma unroll
        for (int j = 0; j < 8; ++j) Vt[(d8 + j) * ALDP + s] = (u16)val[j];
    }
    // zero P pad cols 80..95 (own rows)
    {
        const int row = w * 16 + l15;
        s16x4 z = {0, 0, 0, 0};
        *(s16x4*)&Pls[row * ALDP + 80 + (lhi << 2)] = z;
    }
    __syncthreads();

    // scores S[16 q-rows][80 k-cols] per wave
    f32x4 sacc[5] = {};
#pragma unroll
    for (int kt = 0; kt < 6; ++kt) {
#pragma unroll
        for (int nf = 0; nf < 5; ++nf) {
            f16x8 kf = *(const f16x8*)&Ks[(nf * 16 + l15) * ALDK + kt * 32 + (lhi << 3)];
            sacc[nf] = MFMAH(qf[kt], kf, sacc[nf]);
        }
    }

    // softmax per q-row (row = lhi*4 + r); P kept unnormalized
    float rps[4];
    const float scale = 0.07216878364870323f;   // 192^-0.5
#pragma unroll
    for (int r = 0; r < 4; ++r) {
        float m = -1e30f;
#pragma unroll
        for (int nf = 0; nf < 5; ++nf) {
            const int c = nf * 16 + l15;
            const float sv = sacc[nf][r] * scale;
            if (c < 77) m = fmaxf(m, sv);
        }
#pragma unroll
        for (int off = 1; off < 16; off <<= 1) m = fmaxf(m, __shfl_xor(m, off));
        float sum = 0.f;
#pragma unroll
        for (int nf = 0; nf < 5; ++nf) {
            const int c = nf * 16 + l15;
            const float p = (c < 77) ? __expf(sacc[nf][r] * scale - m) : 0.f;
            sacc[nf][r] = p;
            sum += p;
        }
#pragma unroll
        for (int off = 1; off < 16; off <<= 1) sum += __shfl_xor(sum, off);
        rps[r] = 1.0f / sum;   // sum >= 1
    }

    // write P (own 16 rows)
#pragma unroll
    for (int r = 0; r < 4; ++r)
#pragma unroll
        for (int nf = 0; nf < 5; ++nf)
            Pls[(w * 16 + (lhi << 2) + r) * ALDP + nf * 16 + l15] = f2h(sacc[nf][r]);
    __syncthreads();

    // P A-fragments
    f16x8 pa[3];
#pragma unroll
    for (int kt = 0; kt < 3; ++kt)
        pa[kt] = *(const f16x8*)&Pls[(w * 16 + l15) * ALDP + kt * 32 + (lhi << 3)];

    const size_t orow = (size_t)(b * 1024 + qt * 64 + w * 16 + (lhi << 2));

    // PV half 0 -> O[:, 0:96)
    {
        f32x4 oacc[6] = {};
#pragma unroll
        for (int kt = 0; kt < 3; ++kt)
#pragma unroll
            for (int nf = 0; nf < 6; ++nf) {
                f16x8 vf = *(const f16x8*)&Vt[(nf * 16 + l15) * ALDP + kt * 32 + (lhi << 3)];
                oacc[nf] = MFMAH(pa[kt], vf, oacc[nf]);
            }
#pragma unroll
        for (int nf = 0; nf < 6; ++nf) {
            const int col = h * 192 + nf * 16 + l15;
#pragma unroll
            for (int r = 0; r < 4; ++r)
                obuf[(orow + r) * 1536 + col] = f2h(oacc[nf][r] * rps[r]);
        }
    }
    __syncthreads();
    // stage V^T half 1: d in [96,192)
    for (int c = t; c < 96 * 12; c += 256) {
        const int s = c / 12, d8 = (c - s * 12) << 3;
        s16x8 val = {};
        if (s < 77) val = *(const s16x8*)&vbuf[(size_t)(b * 77 + s) * 1536 + h * 192 + 96 + d8];
#pragma unroll
        for (int j = 0; j < 8; ++j) Vt[(d8 + j) * ALDP + s] = (u16)val[j];
    }
    __syncthreads();
    // PV half 1 -> O[:, 96:192)
    {
        f32x4 oacc[6] = {};
#pragma unroll
        for (int kt = 0; kt < 3; ++kt)
#pragma unroll
            for (int nf = 0; nf < 6; ++nf) {
                f16x8 vf = *(const f16x8*)&Vt[(nf * 16 + l15) * ALDP + kt * 32 + (lhi << 3)];
                oacc[nf] = MFMAH(pa[kt], vf, oacc[nf]);
            }
#pragma unroll
        for (int nf = 0; nf < 6; ++nf) {
            const int col = h * 192 + 96 + nf * 16 + l15;
#pragma unroll
            for (int r = 0; r < 4; ++r)
                obuf[(orow + r) * 1536 + col] = f2h(oacc[nf][r] * rps[r]);
        }
    }
}

// ---------------------------------------------------------------------------
extern "C" void kernel_launch(void* const* d_in, const int* in_sizes, int n_in,
                              void* d_out, int out_size, void* d_ws, size_t ws_size,
                              hipStream_t stream) {
    const float* img  = (const float*)d_in[0];
    const float* text = (const float*)d_in[1];
    const float* Wq   = (const float*)d_in[2];
    const float* bq   = (const float*)d_in[3];
    const float* Wk   = (const float*)d_in[4];
    const float* bk   = (const float*)d_in[5];
    const float* Wv   = (const float*)d_in[6];
    const float* bv   = (const float*)d_in[7];
    const float* Wo   = (const float*)d_in[8];
    const float* bo   = (const float*)d_in[9];

    const size_t imgN = (size_t)32768 * 1536;
    const size_t txtN = (size_t)2464 * 1536;
    const size_t wN   = (size_t)1536 * 1536;

    // ws layout (~230 MB of fp16)
    u16* img_h = (u16*)d_ws;        // [imgN]
    u16* qb    = img_h + imgN;      // [imgN]  q fp16, O overwrites in-place
    u16* txt_h = qb + imgN;         // [txtN]
    u16* Wq_h  = txt_h + txtN;
    u16* Wk_h  = Wq_h + wN;
    u16* Wv_h  = Wk_h + wN;
    u16* Wo_h  = Wv_h + wN;
    u16* kb    = Wo_h + wN;         // [txtN]
    u16* vb    = kb + txtN;         // [txtN]

    // 1) conversions
    hipLaunchKernelGGL(conv_h, dim3((unsigned)(imgN / 8 / 256)), dim3(256),
                       0, stream, img, img_h, (int)(imgN / 8));
    Conv5Args ca;
    ca.x[0] = text; ca.h[0] = txt_h; ca.n8[0] = (int)(txtN / 8);
    ca.x[1] = Wq;   ca.h[1] = Wq_h;  ca.n8[1] = (int)(wN / 8);
    ca.x[2] = Wk;   ca.h[2] = Wk_h;  ca.n8[2] = (int)(wN / 8);
    ca.x[3] = Wv;   ca.h[3] = Wv_h;  ca.n8[3] = (int)(wN / 8);
    ca.x[4] = Wo;   ca.h[4] = Wo_h;  ca.n8[4] = (int)(wN / 8);
    hipLaunchKernelGGL(conv_h5, dim3((unsigned)((txtN / 8 + 255) / 256), 5),
                       dim3(256), 0, stream, ca);

    // 2) q projection (fp16 out)
    hipLaunchKernelGGL((gemm_h_nt<0>), dim3(1536), dim3(256), 0, stream,
                       img_h, Wq_h, bq, (void*)qb, Wq_h, bq, (void*)qb,
                       32768, 1536, 1536, 6);
    // 3) k,v projections fused via grid.z (fp16 out)
    hipLaunchKernelGGL((gemm_h_nt<0>), dim3(120, 1, 2), dim3(256), 0, stream,
                       txt_h, Wk_h, bk, (void*)kb, Wv_h, bv, (void*)vb,
                       2464, 1536, 1536, 6);
    // 4) attention (O in-place over q)
    hipLaunchKernelGGL(attn_fused, dim3(16, 8, 32), dim3(256), 0, stream,
                       qb, kb, vb, qb);
    // 5) output projection (fp32 out)
    hipLaunchKernelGGL((gemm_h_nt<1>), dim3(1536), dim3(256), 0, stream,
                       qb, Wo_h, bo, d_out, Wo_h, bo, d_out,
                       32768, 1536, 1536, 6);
}

// Round 4
// 623.518 us; speedup vs baseline: 2.9628x; 1.0822x over previous
//
#include <hip/hip_runtime.h>
#include <hip/hip_bf16.h>

// ---------------------------------------------------------------------------
// lora_cross_attention, round 4: fp16 single-pass MFMA with pipelined GEMM.
// conv(img,text,W* -> fp16) -> q = img x Wq^T -> k,v (fused, grid.z)
// -> fused attention (fp16, O in-place over q) -> out = O x Wo^T (fp32).
// GEMM: 256x256 tile, BK=32, 8 waves (2x4, each 128x64), double-buffered
// 64 KB LDS, global_load_lds(16B), counted vmcnt across RAW s_barriers
// (loads in flight over barriers - T3/T4), setprio around MFMA (T5),
// both-sides XOR chunk swizzle (T2), XCD-bijective block swizzle (T1).
// ---------------------------------------------------------------------------

typedef unsigned short u16;
typedef _Float16 f16x8 __attribute__((ext_vector_type(8)));
typedef __attribute__((ext_vector_type(8))) short s16x8;
typedef __attribute__((ext_vector_type(4))) float f32x4;
typedef __attribute__((ext_vector_type(4))) short s16x4;

#define MFMAH(a, b, c) __builtin_amdgcn_mfma_f32_16x16x32_f16(a, b, c, 0, 0, 0)

__device__ __forceinline__ u16 f2h(float x) {
    _Float16 h = (_Float16)x;              // v_cvt_f16_f32, RNE
    return __builtin_bit_cast(u16, h);
}

__device__ __forceinline__ void gload16(const u16* g, const u16* l) {
    __builtin_amdgcn_global_load_lds(
        (const __attribute__((address_space(1))) unsigned int*)g,
        (__attribute__((address_space(3))) unsigned int*)l, 16, 0, 0);
}

// ---------------------------------------------------------------------------
// fp32 -> fp16 conversion
// ---------------------------------------------------------------------------
__global__ void conv_h(const float* __restrict__ x, u16* __restrict__ h, int n8) {
    const int i = blockIdx.x * 256 + threadIdx.x;
    if (i >= n8) return;
    const f32x4 a = ((const f32x4*)x)[2 * i];
    const f32x4 b = ((const f32x4*)x)[2 * i + 1];
    u16 o[8];
#pragma unroll
    for (int j = 0; j < 4; ++j) { o[j] = f2h(a[j]); o[4 + j] = f2h(b[j]); }
    *(s16x8*)&h[(size_t)i << 3] = *(s16x8*)o;
}

struct Conv5Args {
    const float* x[5];
    u16* h[5];
    int n8[5];
};

__global__ void conv_h5(Conv5Args A) {
    const int z = blockIdx.y;
    const int i = blockIdx.x * 256 + threadIdx.x;
    if (i >= A.n8[z]) return;
    const float* x = A.x[z];
    const f32x4 a = ((const f32x4*)x)[2 * i];
    const f32x4 b = ((const f32x4*)x)[2 * i + 1];
    u16 o[8];
#pragma unroll
    for (int j = 0; j < 4; ++j) { o[j] = f2h(a[j]); o[4 + j] = f2h(b[j]); }
    *(s16x8*)&A.h[z][(size_t)i << 3] = *(s16x8*)o;
}

// ---------------------------------------------------------------------------
// C[M,N] = A[M,K] x B[N,K]^T + bias, fp16 in, fp32/fp16 out.
// 256x256 tile, BK=32, 512 threads (8 waves 2x4, each 128 rows x 64 cols).
// LDS 64 KB: buf c at u16 offset c*16384: A tile [256][32] @0, B @8192.
// Chunk swizzle: slot s of row r holds global k-chunk s ^ ((r>>1)&3).
// Schedule per K-step: stage(next->buf^1) | vmcnt(4) | barrier |
//   12 ds_read + 32 MFMA (setprio) | lgkmcnt(0) | barrier.
// grid.z selects (B,bias,C) set 0/1 (fuses k and v projections).
// ---------------------------------------------------------------------------
template <int OUTF32>
__global__ __launch_bounds__(512, 2) void gemm_h_nt(
    const u16* __restrict__ A,
    const u16* __restrict__ B0, const float* __restrict__ bias0, void* __restrict__ C0,
    const u16* __restrict__ B1, const float* __restrict__ bias1, void* __restrict__ C1,
    int M, int N, int K, int nby) {
    __shared__ u16 lds[32768];   // 64 KB, double-buffered

    const u16* B = B0; const float* bias = bias0; void* Cout = C0;
    if (blockIdx.z) { B = B1; bias = bias1; Cout = C1; }

    // XCD-bijective block swizzle (m204)
    const int nwg = gridDim.x;
    const int q8 = nwg >> 3, r8 = nwg & 7;
    const int xcd = blockIdx.x & 7, loc = blockIdx.x >> 3;
    const int wgid = (xcd < r8 ? xcd * (q8 + 1) : r8 * (q8 + 1) + (xcd - r8) * q8) + loc;
    const int bx = wgid / nby, by = wgid - bx * nby;
    const int row0 = bx * 256, col0 = by * 256;

    const int t = threadIdx.x, lane = t & 63, w = t >> 6;
    const int wr = w >> 2, wc = w & 3;
    const int l15 = lane & 15, lhi = lane >> 4;

    // staging: 1024 16B-chunks per tensor; thread handles chunks t, 512+t.
    // LDS slot ci holds global k-chunk (ci&3) ^ ((row>>1)&3)  (row = ci>>2).
    const u16* gA[2]; const u16* gB[2];
    const u16 *lA[2], *lB[2];
#pragma unroll
    for (int it = 0; it < 2; ++it) {
        const int ci = it * 512 + t;
        const int row = ci >> 2;
        const int g = (ci & 3) ^ ((row >> 1) & 3);
        int ar = row0 + row; if (ar > M - 1) ar = M - 1;   // tail clamp (stores guarded)
        gA[it] = A + (size_t)ar * K + (g << 3);
        gB[it] = B + (size_t)(col0 + row) * K + (g << 3);
        lA[it] = lds + ci * 8;
        lB[it] = lds + 8192 + ci * 8;
    }

    // fragment read offsets (swizzled, u16 units)
    int aoff[8], boff[4];
#pragma unroll
    for (int mf = 0; mf < 8; ++mf) {
        const int ar = wr * 128 + mf * 16 + l15;
        aoff[mf] = ar * 32 + ((lhi ^ ((ar >> 1) & 3)) << 3);
    }
#pragma unroll
    for (int nf = 0; nf < 4; ++nf) {
        const int br = wc * 64 + nf * 16 + l15;
        boff[nf] = 8192 + br * 32 + ((lhi ^ ((br >> 1) & 3)) << 3);
    }

    f32x4 acc[8][4] = {};
    const int NT = K >> 5;

    // prologue: stage tile 0 -> buf 0
    gload16(gA[0], lA[0]); gload16(gA[1], lA[1]);
    gload16(gB[0], lB[0]); gload16(gB[1], lB[1]);

    for (int tt = 0; tt < NT; ++tt) {
        const int c = tt & 1;
        const int kn = ((tt + 1 < NT) ? tt + 1 : 0) << 5;  // wrap keeps vmcnt uniform
        const int sb = (c ^ 1) << 14;                      // staging buf offset (u16)
        gload16(gA[0] + kn, lA[0] + sb); gload16(gA[1] + kn, lA[1] + sb);
        gload16(gB[0] + kn, lB[0] + sb); gload16(gB[1] + kn, lB[1] + sb);
        // wait current tile's 4 loads (next tile's 4 stay in flight)
        asm volatile("s_waitcnt vmcnt(4)" ::: "memory");
        __builtin_amdgcn_sched_barrier(0);
        __builtin_amdgcn_s_barrier();
        __builtin_amdgcn_sched_barrier(0);

        const int cb = c << 14;
        f16x8 a[8], b[4];
#pragma unroll
        for (int mf = 0; mf < 8; ++mf) a[mf] = *(const f16x8*)&lds[cb + aoff[mf]];
#pragma unroll
        for (int nf = 0; nf < 4; ++nf) b[nf] = *(const f16x8*)&lds[cb + boff[nf]];
        __builtin_amdgcn_s_setprio(1);
#pragma unroll
        for (int nf = 0; nf < 4; ++nf)
#pragma unroll
            for (int mf = 0; mf < 8; ++mf)
                acc[mf][nf] = MFMAH(a[mf], b[nf], acc[mf][nf]);
        __builtin_amdgcn_s_setprio(0);
        // all my ds_reads of buf c retired before signaling buf c reusable
        asm volatile("s_waitcnt lgkmcnt(0)" ::: "memory");
        __builtin_amdgcn_sched_barrier(0);
        __builtin_amdgcn_s_barrier();
        __builtin_amdgcn_sched_barrier(0);
    }
    asm volatile("s_waitcnt vmcnt(0)" ::: "memory");

    // epilogue: +bias, store (C/D: col=lane&15, row=lhi*4+reg)
#pragma unroll
    for (int nf = 0; nf < 4; ++nf) {
        const int col = col0 + wc * 64 + nf * 16 + l15;
        const float bs = bias[col];
#pragma unroll
        for (int mf = 0; mf < 8; ++mf) {
            const int row = row0 + wr * 128 + mf * 16 + (lhi << 2);
#pragma unroll
            for (int r = 0; r < 4; ++r) {
                if (row + r < M) {
                    const float v = acc[mf][nf][r] + bs;
                    if (OUTF32) ((float*)Cout)[(size_t)(row + r) * N + col] = v;
                    else        ((u16*)Cout)[(size_t)(row + r) * N + col] = f2h(v);
                }
            }
        }
    }
}

// ---------------------------------------------------------------------------
// Fused attention, fp16 in/out. One block per (qtile=64,h,b), 4 waves x 16
// q-rows. Sk=77 one-shot. O written IN-PLACE over q (each wave reads exactly
// the rows+head-slice it later writes; Q register-resident first).
// ---------------------------------------------------------------------------
#define ALDK 200
#define ALDP 104

__global__ void attn_fused(const u16* __restrict__ qbuf, const u16* __restrict__ kbuf,
                           const u16* __restrict__ vbuf, u16* __restrict__ obuf) {
    __shared__ u16 Ks[80 * ALDK];   // 32000 B
    __shared__ u16 Pls[64 * ALDP];  // 13312 B
    __shared__ u16 Vt[96 * ALDP];   // 19968 B (65280 total)

    const int t = threadIdx.x, lane = t & 63, w = t >> 6;
    const int qt = blockIdx.x, h = blockIdx.y, b = blockIdx.z;
    const int l15 = lane & 15, lhi = lane >> 4;

    // Q fragments straight from global fp16
    f16x8 qf[6];
    {
        const size_t qrow = (size_t)(b * 1024 + qt * 64 + w * 16 + l15);
        const u16* qp = qbuf + qrow * 1536 + h * 192 + (lhi << 3);
#pragma unroll
        for (int kt = 0; kt < 6; ++kt) qf[kt] = *(const f16x8*)(qp + kt * 32);
    }

    // stage K [80][192], rows >=77 zero
    for (int c = t; c < 80 * 24; c += 256) {
        const int s = c / 24, d8 = (c - s * 24) << 3;
        s16x8 val = {};
        if (s < 77) val = *(const s16x8*)&kbuf[(size_t)(b * 77 + s) * 1536 + h * 192 + d8];
        *(s16x8*)&Ks[s * ALDK + d8] = val;
    }
    // stage V^T half 0: d in [0,96).  s varies fastest across lanes ->
    // scatter writes stride 2B = conflict-free (was 12-way on d-stride).
    for (int c = t; c < 96 * 12; c += 256) {
        const int s = c % 96, d8 = (c / 96) << 3;
        s16x8 val = {};
        if (s < 77) val = *(const s16x8*)&vbuf[(size_t)(b * 77 + s) * 1536 + h * 192 + d8];
#pragma unroll
        for (int j = 0; j < 8; ++j) Vt[(d8 + j) * ALDP + s] = (u16)val[j];
    }
    // zero P pad cols 80..95 (own rows)
    {
        const int row = w * 16 + l15;
        s16x4 z = {0, 0, 0, 0};
        *(s16x4*)&Pls[row * ALDP + 80 + (lhi << 2)] = z;
    }
    __syncthreads();

    // scores S[16 q-rows][80 k-cols] per wave
    f32x4 sacc[5] = {};
#pragma unroll
    for (int kt = 0; kt < 6; ++kt) {
#pragma unroll
        for (int nf = 0; nf < 5; ++nf) {
            f16x8 kf = *(const f16x8*)&Ks[(nf * 16 + l15) * ALDK + kt * 32 + (lhi << 3)];
            sacc[nf] = MFMAH(qf[kt], kf, sacc[nf]);
        }
    }

    // softmax per q-row (row = lhi*4 + r); P kept unnormalized
    float rps[4];
    const float scale = 0.07216878364870323f;   // 192^-0.5
#pragma unroll
    for (int r = 0; r < 4; ++r) {
        float m = -1e30f;
#pragma unroll
        for (int nf = 0; nf < 5; ++nf) {
            const int c = nf * 16 + l15;
            const float sv = sacc[nf][r] * scale;
            if (c < 77) m = fmaxf(m, sv);
        }
#pragma unroll
        for (int off = 1; off < 16; off <<= 1) m = fmaxf(m, __shfl_xor(m, off));
        float sum = 0.f;
#pragma unroll
        for (int nf = 0; nf < 5; ++nf) {
            const int c = nf * 16 + l15;
            const float p = (c < 77) ? __expf(sacc[nf][r] * scale - m) : 0.f;
            sacc[nf][r] = p;
            sum += p;
        }
#pragma unroll
        for (int off = 1; off < 16; off <<= 1) sum += __shfl_xor(sum, off);
        rps[r] = 1.0f / sum;   // sum >= 1
    }

    // write P (own 16 rows)
#pragma unroll
    for (int r = 0; r < 4; ++r)
#pragma unroll
        for (int nf = 0; nf < 5; ++nf)
            Pls[(w * 16 + (lhi << 2) + r) * ALDP + nf * 16 + l15] = f2h(sacc[nf][r]);
    __syncthreads();

    // P A-fragments
    f16x8 pa[3];
#pragma unroll
    for (int kt = 0; kt < 3; ++kt)
        pa[kt] = *(const f16x8*)&Pls[(w * 16 + l15) * ALDP + kt * 32 + (lhi << 3)];

    const size_t orow = (size_t)(b * 1024 + qt * 64 + w * 16 + (lhi << 2));

    // PV half 0 -> O[:, 0:96)
    {
        f32x4 oacc[6] = {};
#pragma unroll
        for (int kt = 0; kt < 3; ++kt)
#pragma unroll
            for (int nf = 0; nf < 6; ++nf) {
                f16x8 vf = *(const f16x8*)&Vt[(nf * 16 + l15) * ALDP + kt * 32 + (lhi << 3)];
                oacc[nf] = MFMAH(pa[kt], vf, oacc[nf]);
            }
#pragma unroll
        for (int nf = 0; nf < 6; ++nf) {
            const int col = h * 192 + nf * 16 + l15;
#pragma unroll
            for (int r = 0; r < 4; ++r)
                obuf[(orow + r) * 1536 + col] = f2h(oacc[nf][r] * rps[r]);
        }
    }
    __syncthreads();
    // stage V^T half 1: d in [96,192)
    for (int c = t; c < 96 * 12; c += 256) {
        const int s = c % 96, d8 = (c / 96) << 3;
        s16x8 val = {};
        if (s < 77) val = *(const s16x8*)&vbuf[(size_t)(b * 77 + s) * 1536 + h * 192 + 96 + d8];
#pragma unroll
        for (int j = 0; j < 8; ++j) Vt[(d8 + j) * ALDP + s] = (u16)val[j];
    }
    __syncthreads();
    // PV half 1 -> O[:, 96:192)
    {
        f32x4 oacc[6] = {};
#pragma unroll
        for (int kt = 0; kt < 3; ++kt)
#pragma unroll
            for (int nf = 0; nf < 6; ++nf) {
                f16x8 vf = *(const f16x8*)&Vt[(nf * 16 + l15) * ALDP + kt * 32 + (lhi << 3)];
                oacc[nf] = MFMAH(pa[kt], vf, oacc[nf]);
            }
#pragma unroll
        for (int nf = 0; nf < 6; ++nf) {
            const int col = h * 192 + 96 + nf * 16 + l15;
#pragma unroll
            for (int r = 0; r < 4; ++r)
                obuf[(orow + r) * 1536 + col] = f2h(oacc[nf][r] * rps[r]);
        }
    }
}

// ---------------------------------------------------------------------------
extern "C" void kernel_launch(void* const* d_in, const int* in_sizes, int n_in,
                              void* d_out, int out_size, void* d_ws, size_t ws_size,
                              hipStream_t stream) {
    const float* img  = (const float*)d_in[0];
    const float* text = (const float*)d_in[1];
    const float* Wq   = (const float*)d_in[2];
    const float* bq   = (const float*)d_in[3];
    const float* Wk   = (const float*)d_in[4];
    const float* bk   = (const float*)d_in[5];
    const float* Wv   = (const float*)d_in[6];
    const float* bv   = (const float*)d_in[7];
    const float* Wo   = (const float*)d_in[8];
    const float* bo   = (const float*)d_in[9];

    const size_t imgN = (size_t)32768 * 1536;
    const size_t txtN = (size_t)2464 * 1536;
    const size_t wN   = (size_t)1536 * 1536;

    // ws layout (~230 MB of fp16)
    u16* img_h = (u16*)d_ws;        // [imgN]
    u16* qb    = img_h + imgN;      // [imgN]  q fp16, O overwrites in-place
    u16* txt_h = qb + imgN;         // [txtN]
    u16* Wq_h  = txt_h + txtN;
    u16* Wk_h  = Wq_h + wN;
    u16* Wv_h  = Wk_h + wN;
    u16* Wo_h  = Wv_h + wN;
    u16* kb    = Wo_h + wN;         // [txtN]
    u16* vb    = kb + txtN;         // [txtN]

    // 1) conversions
    hipLaunchKernelGGL(conv_h, dim3((unsigned)(imgN / 8 / 256)), dim3(256),
                       0, stream, img, img_h, (int)(imgN / 8));
    Conv5Args ca;
    ca.x[0] = text; ca.h[0] = txt_h; ca.n8[0] = (int)(txtN / 8);
    ca.x[1] = Wq;   ca.h[1] = Wq_h;  ca.n8[1] = (int)(wN / 8);
    ca.x[2] = Wk;   ca.h[2] = Wk_h;  ca.n8[2] = (int)(wN / 8);
    ca.x[3] = Wv;   ca.h[3] = Wv_h;  ca.n8[3] = (int)(wN / 8);
    ca.x[4] = Wo;   ca.h[4] = Wo_h;  ca.n8[4] = (int)(wN / 8);
    hipLaunchKernelGGL(conv_h5, dim3((unsigned)((txtN / 8 + 255) / 256), 5),
                       dim3(256), 0, stream, ca);

    // 2) q projection (fp16 out): 128 x 6 tiles of 256x256
    hipLaunchKernelGGL((gemm_h_nt<0>), dim3(768), dim3(512), 0, stream,
                       img_h, Wq_h, bq, (void*)qb, Wq_h, bq, (void*)qb,
                       32768, 1536, 1536, 6);
    // 3) k,v projections fused via grid.z (fp16 out): 10 x 6 tiles
    hipLaunchKernelGGL((gemm_h_nt<0>), dim3(60, 1, 2), dim3(512), 0, stream,
                       txt_h, Wk_h, bk, (void*)kb, Wv_h, bv, (void*)vb,
                       2464, 1536, 1536, 6);
    // 4) attention (O in-place over q)
    hipLaunchKernelGGL(attn_fused, dim3(16, 8, 32), dim3(256), 0, stream,
                       qb, kb, vb, qb);
    // 5) output projection (fp32 out)
    hipLaunchKernelGGL((gemm_h_nt<1>), dim3(768), dim3(512), 0, stream,
                       qb, Wo_h, bo, d_out, Wo_h, bo, d_out,
                       32768, 1536, 1536, 6);
}

// Round 5
// 587.835 us; speedup vs baseline: 3.1426x; 1.0607x over previous
//
#include <hip/hip_runtime.h>
#include <hip/hip_bf16.h>

// ---------------------------------------------------------------------------
// lora_cross_attention, round 5: fp16 MFMA with the 8-phase m201 GEMM.
// conv(img,text,W* -> fp16) -> q = img x Wq^T -> k,v (fused, grid.z)
// -> fused attention (fp16, O in-place over q) -> out = O x Wo^T (fp32).
// GEMM: 256x256 tile, BK=64, 8 waves (2x4, each 128x64), 128 KB dbuf LDS,
// 4 phases/K-tile {ds_read subtile | stage half-tile | bar | lgkm0 |
// setprio+16 MFMA | bar}, counted vmcnt(2) once per K-tile (loads stay in
// flight across barriers), chunk-XOR swizzle both sides, XCD swizzle.
// ---------------------------------------------------------------------------

typedef unsigned short u16;
typedef _Float16 f16x8 __attribute__((ext_vector_type(8)));
typedef __attribute__((ext_vector_type(8))) short s16x8;
typedef __attribute__((ext_vector_type(4))) float f32x4;
typedef __attribute__((ext_vector_type(4))) short s16x4;

#define MFMAH(a, b, c) __builtin_amdgcn_mfma_f32_16x16x32_f16(a, b, c, 0, 0, 0)

__device__ __forceinline__ u16 f2h(float x) {
    _Float16 h = (_Float16)x;              // v_cvt_f16_f32, RNE
    return __builtin_bit_cast(u16, h);
}

__device__ __forceinline__ void gload16(const u16* g, const u16* l) {
    __builtin_amdgcn_global_load_lds(
        (const __attribute__((address_space(1))) unsigned int*)g,
        (__attribute__((address_space(3))) unsigned int*)l, 16, 0, 0);
}

// ---------------------------------------------------------------------------
// fp32 -> fp16 conversion
// ---------------------------------------------------------------------------
__global__ void conv_h(const float* __restrict__ x, u16* __restrict__ h, int n8) {
    const int i = blockIdx.x * 256 + threadIdx.x;
    if (i >= n8) return;
    const f32x4 a = ((const f32x4*)x)[2 * i];
    const f32x4 b = ((const f32x4*)x)[2 * i + 1];
    u16 o[8];
#pragma unroll
    for (int j = 0; j < 4; ++j) { o[j] = f2h(a[j]); o[4 + j] = f2h(b[j]); }
    *(s16x8*)&h[(size_t)i << 3] = *(s16x8*)o;
}

struct Conv5Args {
    const float* x[5];
    u16* h[5];
    int n8[5];
};

__global__ void conv_h5(Conv5Args A) {
    const int z = blockIdx.y;
    const int i = blockIdx.x * 256 + threadIdx.x;
    if (i >= A.n8[z]) return;
    const float* x = A.x[z];
    const f32x4 a = ((const f32x4*)x)[2 * i];
    const f32x4 b = ((const f32x4*)x)[2 * i + 1];
    u16 o[8];
#pragma unroll
    for (int j = 0; j < 4; ++j) { o[j] = f2h(a[j]); o[4 + j] = f2h(b[j]); }
    *(s16x8*)&A.h[z][(size_t)i << 3] = *(s16x8*)o;
}

// ---------------------------------------------------------------------------
// C[M,N] = A[M,K] x B[N,K]^T + bias, fp16 in, fp32/fp16 out.
// 256x256 tile, BK=64, 512 threads (8 waves 2x4, each 128 rows x 64 cols).
// LDS 128 KB: buf c at u16 offset c*32768; A tile [256][64] @+0, B @+16384.
// Row r, 16B-chunk slot s holds global k-chunk s ^ (r&7)  (both-sides swz).
// grid.z selects (B,bias,C) set 0/1 (fuses k and v projections).
// ---------------------------------------------------------------------------
template <int OUTF32>
__global__ __launch_bounds__(512, 2) void gemm_h_nt(
    const u16* __restrict__ A,
    const u16* __restrict__ B0, const float* __restrict__ bias0, void* __restrict__ C0,
    const u16* __restrict__ B1, const float* __restrict__ bias1, void* __restrict__ C1,
    int M, int N, int K, int nby) {
    __shared__ u16 lds[65536];   // 128 KB, double-buffered

    const u16* B = B0; const float* bias = bias0; void* Cout = C0;
    if (blockIdx.z) { B = B1; bias = bias1; Cout = C1; }

    // XCD-bijective block swizzle (m204)
    const int nwg = gridDim.x;
    const int q8 = nwg >> 3, r8 = nwg & 7;
    const int xcd = blockIdx.x & 7, loc = blockIdx.x >> 3;
    const int wgid = (xcd < r8 ? xcd * (q8 + 1) : r8 * (q8 + 1) + (xcd - r8) * q8) + loc;
    const int bx = wgid / nby, by = wgid - bx * nby;
    const int row0 = bx * 256, col0 = by * 256;

    const int t = threadIdx.x, lane = t & 63, w = t >> 6;
    const int wr = w >> 2, wc = w & 3;
    const int l15 = lane & 15, lhi = lane >> 4;

    // staging: half-tiles h0=A[0:128) h1=A[128:256) h2=B[0:128) h3=B[128:256).
    // Each = 1024 16B-chunks; thread t owns chunks t and 512+t.
    const u16* gp[4][2];
    int lof[4][2];
#pragma unroll
    for (int p = 0; p < 4; ++p)
#pragma unroll
        for (int it = 0; it < 2; ++it) {
            const int ci = it * 512 + t;
            const int rih = ci >> 3, slot = ci & 7;
            const int gs = slot ^ (rih & 7);
            if (p < 2) {
                int gr = row0 + p * 128 + rih;
                if (gr > M - 1) gr = M - 1;          // tail clamp (stores guarded)
                gp[p][it] = A + (size_t)gr * K + (gs << 3);
                lof[p][it] = p * 8192 + ci * 8;
            } else {
                const int gr = col0 + (p - 2) * 128 + rih;
                gp[p][it] = B + (size_t)gr * K + (gs << 3);
                lof[p][it] = 16384 + (p - 2) * 8192 + ci * 8;
            }
        }

    // fragment read offsets (k-slice 0; k-slice 1 = ^32 since chunk bit2 flips)
    int aof[8], bof[4];
#pragma unroll
    for (int i = 0; i < 8; ++i) {
        const int ar = wr * 128 + i * 16 + l15;
        aof[i] = ar * 64 + ((lhi ^ (ar & 7)) << 3);
    }
#pragma unroll
    for (int n = 0; n < 4; ++n) {
        const int br = wc * 64 + n * 16 + l15;
        bof[n] = 16384 + br * 64 + ((lhi ^ (br & 7)) << 3);
    }

    f32x4 acc[8][4] = {};
    const int NT = K >> 6;

    // prologue: stage tile 0 -> buf 0
#pragma unroll
    for (int p = 0; p < 4; ++p) {
        gload16(gp[p][0], lds + lof[p][0]);
        gload16(gp[p][1], lds + lof[p][1]);
    }

#define STAGE(p) do { gload16(gp[p][0] + kn, lsb + lof[p][0]); \
                      gload16(gp[p][1] + kn, lsb + lof[p][1]); } while (0)
#define BARX() do { __builtin_amdgcn_sched_barrier(0); __builtin_amdgcn_s_barrier(); \
                    __builtin_amdgcn_sched_barrier(0); } while (0)
#define LGKM0() do { asm volatile("s_waitcnt lgkmcnt(0)" ::: "memory"); \
                     __builtin_amdgcn_sched_barrier(0); } while (0)
#define MFMA_Q(mh) do { __builtin_amdgcn_s_setprio(1); \
    _Pragma("unroll") for (int nf = 0; nf < 4; ++nf) \
    _Pragma("unroll") for (int mf = 0; mf < 4; ++mf) \
        acc[(mh) * 4 + mf][nf] = MFMAH(a[mf], bb[nf], acc[(mh) * 4 + mf][nf]); \
    __builtin_amdgcn_s_setprio(0); } while (0)

    for (int tt = 0; tt < NT; ++tt) {
        const int cb = (tt & 1) << 15;
        u16* lsb = lds + (((tt & 1) ^ 1) << 15);
        const size_t kn = (size_t)((tt + 1 < NT) ? tt + 1 : 0) << 6;  // wrap: vmcnt uniform

        f16x8 a[4], bb[4];

        // ---- phase 0: stage h0(next); vmcnt(2) [cur tile's 8 landed, 2 in
        //      flight]; bar; read B k0 + A(mh0) k0; mfma rows 0-3 x k0
        STAGE(0);
        asm volatile("s_waitcnt vmcnt(2)" ::: "memory");
        BARX();
#pragma unroll
        for (int nf = 0; nf < 4; ++nf) bb[nf] = *(const f16x8*)&lds[cb + bof[nf]];
#pragma unroll
        for (int mf = 0; mf < 4; ++mf) a[mf] = *(const f16x8*)&lds[cb + aof[mf]];
        LGKM0();
        MFMA_Q(0);
        BARX();
        // ---- phase 1: read A(mh1) k0; stage h1; mfma rows 4-7 x k0
#pragma unroll
        for (int mf = 0; mf < 4; ++mf) a[mf] = *(const f16x8*)&lds[cb + aof[4 + mf]];
        STAGE(1);
        BARX();
        LGKM0();
        MFMA_Q(1);
        BARX();
        // ---- phase 2: read B k1 + A(mh0) k1; stage h2; mfma rows 0-3 x k1
#pragma unroll
        for (int nf = 0; nf < 4; ++nf) bb[nf] = *(const f16x8*)&lds[cb + (bof[nf] ^ 32)];
#pragma unroll
        for (int mf = 0; mf < 4; ++mf) a[mf] = *(const f16x8*)&lds[cb + (aof[mf] ^ 32)];
        STAGE(2);
        BARX();
        LGKM0();
        MFMA_Q(0);
        BARX();
        // ---- phase 3: read A(mh1) k1; stage h3; mfma rows 4-7 x k1
#pragma unroll
        for (int mf = 0; mf < 4; ++mf) a[mf] = *(const f16x8*)&lds[cb + (aof[4 + mf] ^ 32)];
        STAGE(3);
        BARX();
        LGKM0();
        MFMA_Q(1);
        BARX();
    }
    asm volatile("s_waitcnt vmcnt(0)" ::: "memory");

    // epilogue: +bias, store (C/D: col=lane&15, row=lhi*4+reg)
#pragma unroll
    for (int nf = 0; nf < 4; ++nf) {
        const int col = col0 + wc * 64 + nf * 16 + l15;
        const float bs = bias[col];
#pragma unroll
        for (int mf = 0; mf < 8; ++mf) {
            const int row = row0 + wr * 128 + mf * 16 + (lhi << 2);
#pragma unroll
            for (int r = 0; r < 4; ++r) {
                if (row + r < M) {
                    const float v = acc[mf][nf][r] + bs;
                    if (OUTF32) ((float*)Cout)[(size_t)(row + r) * N + col] = v;
                    else        ((u16*)Cout)[(size_t)(row + r) * N + col] = f2h(v);
                }
            }
        }
    }
#undef STAGE
#undef BARX
#undef LGKM0
#undef MFMA_Q
}

// ---------------------------------------------------------------------------
// Fused attention, fp16 in/out. One block per (qtile=64,h,b), 4 waves x 16
// q-rows. Sk=77 one-shot. O written IN-PLACE over q (each wave reads exactly
// the rows+head-slice it later writes; Q register-resident first).
// ---------------------------------------------------------------------------
#define ALDK 200
#define ALDP 104

__global__ void attn_fused(const u16* __restrict__ qbuf, const u16* __restrict__ kbuf,
                           const u16* __restrict__ vbuf, u16* __restrict__ obuf) {
    __shared__ u16 Ks[80 * ALDK];   // 32000 B
    __shared__ u16 Pls[64 * ALDP];  // 13312 B
    __shared__ u16 Vt[96 * ALDP];   // 19968 B (65280 total)

    const int t = threadIdx.x, lane = t & 63, w = t >> 6;
    const int qt = blockIdx.x, h = blockIdx.y, b = blockIdx.z;
    const int l15 = lane & 15, lhi = lane >> 4;

    // Q fragments straight from global fp16
    f16x8 qf[6];
    {
        const size_t qrow = (size_t)(b * 1024 + qt * 64 + w * 16 + l15);
        const u16* qp = qbuf + qrow * 1536 + h * 192 + (lhi << 3);
#pragma unroll
        for (int kt = 0; kt < 6; ++kt) qf[kt] = *(const f16x8*)(qp + kt * 32);
    }

    // stage K [80][192], rows >=77 zero
    for (int c = t; c < 80 * 24; c += 256) {
        const int s = c / 24, d8 = (c - s * 24) << 3;
        s16x8 val = {};
        if (s < 77) val = *(const s16x8*)&kbuf[(size_t)(b * 77 + s) * 1536 + h * 192 + d8];
        *(s16x8*)&Ks[s * ALDK + d8] = val;
    }
    // stage V^T half 0: d in [0,96); s fastest across lanes (conflict-free)
    for (int c = t; c < 96 * 12; c += 256) {
        const int s = c % 96, d8 = (c / 96) << 3;
        s16x8 val = {};
        if (s < 77) val = *(const s16x8*)&vbuf[(size_t)(b * 77 + s) * 1536 + h * 192 + d8];
#pragma unroll
        for (int j = 0; j < 8; ++j) Vt[(d8 + j) * ALDP + s] = (u16)val[j];
    }
    // zero P pad cols 80..95 (own rows)
    {
        const int row = w * 16 + l15;
        s16x4 z = {0, 0, 0, 0};
        *(s16x4*)&Pls[row * ALDP + 80 + (lhi << 2)] = z;
    }
    __syncthreads();

    // scores S[16 q-rows][80 k-cols] per wave
    f32x4 sacc[5] = {};
#pragma unroll
    for (int kt = 0; kt < 6; ++kt) {
#pragma unroll
        for (int nf = 0; nf < 5; ++nf) {
            f16x8 kf = *(const f16x8*)&Ks[(nf * 16 + l15) * ALDK + kt * 32 + (lhi << 3)];
            sacc[nf] = MFMAH(qf[kt], kf, sacc[nf]);
        }
    }

    // softmax per q-row (row = lhi*4 + r); P kept unnormalized
    float rps[4];
    const float scale = 0.07216878364870323f;   // 192^-0.5
#pragma unroll
    for (int r = 0; r < 4; ++r) {
        float m = -1e30f;
#pragma unroll
        for (int nf = 0; nf < 5; ++nf) {
            const int c = nf * 16 + l15;
            const float sv = sacc[nf][r] * scale;
            if (c < 77) m = fmaxf(m, sv);
        }
#pragma unroll
        for (int off = 1; off < 16; off <<= 1) m = fmaxf(m, __shfl_xor(m, off));
        float sum = 0.f;
#pragma unroll
        for (int nf = 0; nf < 5; ++nf) {
            const int c = nf * 16 + l15;
            const float p = (c < 77) ? __expf(sacc[nf][r] * scale - m) : 0.f;
            sacc[nf][r] = p;
            sum += p;
        }
#pragma unroll
        for (int off = 1; off < 16; off <<= 1) sum += __shfl_xor(sum, off);
        rps[r] = 1.0f / sum;   // sum >= 1
    }

    // write P (own 16 rows)
#pragma unroll
    for (int r = 0; r < 4; ++r)
#pragma unroll
        for (int nf = 0; nf < 5; ++nf)
            Pls[(w * 16 + (lhi << 2) + r) * ALDP + nf * 16 + l15] = f2h(sacc[nf][r]);
    __syncthreads();

    // P A-fragments
    f16x8 pa[3];
#pragma unroll
    for (int kt = 0; kt < 3; ++kt)
        pa[kt] = *(const f16x8*)&Pls[(w * 16 + l15) * ALDP + kt * 32 + (lhi << 3)];

    const size_t orow = (size_t)(b * 1024 + qt * 64 + w * 16 + (lhi << 2));

    // PV half 0 -> O[:, 0:96)
    {
        f32x4 oacc[6] = {};
#pragma unroll
        for (int kt = 0; kt < 3; ++kt)
#pragma unroll
            for (int nf = 0; nf < 6; ++nf) {
                f16x8 vf = *(const f16x8*)&Vt[(nf * 16 + l15) * ALDP + kt * 32 + (lhi << 3)];
                oacc[nf] = MFMAH(pa[kt], vf, oacc[nf]);
            }
#pragma unroll
        for (int nf = 0; nf < 6; ++nf) {
            const int col = h * 192 + nf * 16 + l15;
#pragma unroll
            for (int r = 0; r < 4; ++r)
                obuf[(orow + r) * 1536 + col] = f2h(oacc[nf][r] * rps[r]);
        }
    }
    __syncthreads();
    // stage V^T half 1: d in [96,192)
    for (int c = t; c < 96 * 12; c += 256) {
        const int s = c % 96, d8 = (c / 96) << 3;
        s16x8 val = {};
        if (s < 77) val = *(const s16x8*)&vbuf[(size_t)(b * 77 + s) * 1536 + h * 192 + 96 + d8];
#pragma unroll
        for (int j = 0; j < 8; ++j) Vt[(d8 + j) * ALDP + s] = (u16)val[j];
    }
    __syncthreads();
    // PV half 1 -> O[:, 96:192)
    {
        f32x4 oacc[6] = {};
#pragma unroll
        for (int kt = 0; kt < 3; ++kt)
#pragma unroll
            for (int nf = 0; nf < 6; ++nf) {
                f16x8 vf = *(const f16x8*)&Vt[(nf * 16 + l15) * ALDP + kt * 32 + (lhi << 3)];
                oacc[nf] = MFMAH(pa[kt], vf, oacc[nf]);
            }
#pragma unroll
        for (int nf = 0; nf < 6; ++nf) {
            const int col = h * 192 + 96 + nf * 16 + l15;
#pragma unroll
            for (int r = 0; r < 4; ++r)
                obuf[(orow + r) * 1536 + col] = f2h(oacc[nf][r] * rps[r]);
        }
    }
}

// ---------------------------------------------------------------------------
extern "C" void kernel_launch(void* const* d_in, const int* in_sizes, int n_in,
                              void* d_out, int out_size, void* d_ws, size_t ws_size,
                              hipStream_t stream) {
    const float* img  = (const float*)d_in[0];
    const float* text = (const float*)d_in[1];
    const float* Wq   = (const float*)d_in[2];
    const float* bq   = (const float*)d_in[3];
    const float* Wk   = (const float*)d_in[4];
    const float* bk   = (const float*)d_in[5];
    const float* Wv   = (const float*)d_in[6];
    const float* bv   = (const float*)d_in[7];
    const float* Wo   = (const float*)d_in[8];
    const float* bo   = (const float*)d_in[9];

    const size_t imgN = (size_t)32768 * 1536;
    const size_t txtN = (size_t)2464 * 1536;
    const size_t wN   = (size_t)1536 * 1536;

    // ws layout (~230 MB of fp16)
    u16* img_h = (u16*)d_ws;        // [imgN]
    u16* qb    = img_h + imgN;      // [imgN]  q fp16, O overwrites in-place
    u16* txt_h = qb + imgN;         // [txtN]
    u16* Wq_h  = txt_h + txtN;
    u16* Wk_h  = Wq_h + wN;
    u16* Wv_h  = Wk_h + wN;
    u16* Wo_h  = Wv_h + wN;
    u16* kb    = Wo_h + wN;         // [txtN]
    u16* vb    = kb + txtN;         // [txtN]

    // 1) conversions
    hipLaunchKernelGGL(conv_h, dim3((unsigned)(imgN / 8 / 256)), dim3(256),
                       0, stream, img, img_h, (int)(imgN / 8));
    Conv5Args ca;
    ca.x[0] = text; ca.h[0] = txt_h; ca.n8[0] = (int)(txtN / 8);
    ca.x[1] = Wq;   ca.h[1] = Wq_h;  ca.n8[1] = (int)(wN / 8);
    ca.x[2] = Wk;   ca.h[2] = Wk_h;  ca.n8[2] = (int)(wN / 8);
    ca.x[3] = Wv;   ca.h[3] = Wv_h;  ca.n8[3] = (int)(wN / 8);
    ca.x[4] = Wo;   ca.h[4] = Wo_h;  ca.n8[4] = (int)(wN / 8);
    hipLaunchKernelGGL(conv_h5, dim3((unsigned)((txtN / 8 + 255) / 256), 5),
                       dim3(256), 0, stream, ca);

    // 2) q projection (fp16 out): 128 x 6 tiles of 256x256
    hipLaunchKernelGGL((gemm_h_nt<0>), dim3(768), dim3(512), 0, stream,
                       img_h, Wq_h, bq, (void*)qb, Wq_h, bq, (void*)qb,
                       32768, 1536, 1536, 6);
    // 3) k,v projections fused via grid.z (fp16 out): 10 x 6 tiles
    hipLaunchKernelGGL((gemm_h_nt<0>), dim3(60, 1, 2), dim3(512), 0, stream,
                       txt_h, Wk_h, bk, (void*)kb, Wv_h, bv, (void*)vb,
                       2464, 1536, 1536, 6);
    // 4) attention (O in-place over q)
    hipLaunchKernelGGL(attn_fused, dim3(16, 8, 32), dim3(256), 0, stream,
                       qb, kb, vb, qb);
    // 5) output projection (fp32 out)
    hipLaunchKernelGGL((gemm_h_nt<1>), dim3(768), dim3(512), 0, stream,
                       qb, Wo_h, bo, d_out, Wo_h, bo, d_out,
                       32768, 1536, 1536, 6);
}